// Round 4
// baseline (546.383 us; speedup 1.0000x reference)
//
#include <hip/hip_runtime.h>
#include <math.h>

#define N      128
#define NS     16
#define NC     4
#define NT     4
#define NPIX   (N * N)       // 16384

// cis(2*pi*rev) via libm sincosf on a range-reduced radian argument.
__device__ __forceinline__ void cis_rev(float rev, float& c, float& s) {
    float f = rev - rintf(rev);                  // [-0.5, 0.5]
    float ang = 6.28318530717958647692f * f;     // [-pi, pi]
    float ss, cc;
    sincosf(ang, &ss, &cc);
    s = ss;
    c = cc;
}

// P[t][i][j][c] = csm[c,i,j] * im_t[i,j], im_t = nearest-neighbor warp of x.
__global__ __launch_bounds__(256) void prep_kernel(
    const float* __restrict__ x, const float* __restrict__ csm,
    const float* __restrict__ flow, float* __restrict__ P)
{
    int g = blockIdx.x * 256 + threadIdx.x;   // 0 .. NT*NPIX-1
    int t = g >> 14;                          // g / 16384
    int p = g & (NPIX - 1);
    int i = p >> 7, j = p & (N - 1);
    // flow layout [i][j][2][t]
    float f0 = flow[(p * 2 + 0) * NT + t];
    float f1 = flow[(p * 2 + 1) * NT + t];
    int si = (int)rintf((float)i + f0); si = min(max(si, 0), N - 1);
    int sj = (int)rintf((float)j + f1); sj = min(max(sj, 0), N - 1);
    float im = x[si * N + sj];
    float4 v;
    v.x = csm[0 * NPIX + p] * im;
    v.y = csm[1 * NPIX + p] * im;
    v.z = csm[2 * NPIX + p] * im;
    v.w = csm[3 * NPIX + p] * im;
    ((float4*)P)[g] = v;
}

// MODE 0: out_size==8192 world — harness compares real part only; write
//         Re densely at q=(r*NS+sp)*NC+c.
// MODE 1: out_size==16384 world — interleaved complex floats, with kx/ky
//         pairing swapped (probe for coordinate-pairing bug).
template <int MODE>
__global__ __launch_bounds__(256) void ndft_kernel(
    const float* __restrict__ traj, const float* __restrict__ P,
    float* __restrict__ out, int out_size)
{
    int b = blockIdx.x;            // 256 blocks
    int t = b & 3;
    int chunk = b >> 2;            // 0..63, 32 m-points each
    int tid = threadIdx.x;
    int m_local = tid >> 3;        // 0..31
    int jj = tid & 7;              // 0..7
    int m = chunk * 32 + m_local;
    int sp = m >> 7;               // spoke index (m = sp*128 + r)
    int r  = m & (N - 1);
    // traj layout [sp][r][t][2]
    float k0 = traj[((sp * N + r) * NT + t) * 2 + 0];
    float k1 = traj[((sp * N + r) * NT + t) * 2 + 1];
    float kx = (MODE == 1) ? k1 : k0;   // pairs with row coord (i-64)
    float ky = (MODE == 1) ? k0 : k1;   // pairs with col coord (j-64)

    // Ey register table for this thread's j set: j = jj + 8*s
    float eyr[16], eyi[16];
#pragma unroll
    for (int s = 0; s < 16; ++s) {
        float dj = (float)(jj + 8 * s) - 64.0f;
        cis_rev(-ky * dj, eyr[s], eyi[s]);
    }

    float accr[NC] = {0.f, 0.f, 0.f, 0.f};
    float acci[NC] = {0.f, 0.f, 0.f, 0.f};
    const float4* Pt = (const float4*)P + t * NPIX;

    for (int i = 0; i < N; ++i) {
        float exr, exi;
        cis_rev(-kx * ((float)i - 64.0f), exr, exi);
        float rr[NC] = {0.f, 0.f, 0.f, 0.f};
        float ri[NC] = {0.f, 0.f, 0.f, 0.f};
#pragma unroll
        for (int s = 0; s < 16; ++s) {
            int j = jj + 8 * s;
            float4 pv = Pt[i * N + j];
            rr[0] = fmaf(eyr[s], pv.x, rr[0]); ri[0] = fmaf(eyi[s], pv.x, ri[0]);
            rr[1] = fmaf(eyr[s], pv.y, rr[1]); ri[1] = fmaf(eyi[s], pv.y, ri[1]);
            rr[2] = fmaf(eyr[s], pv.z, rr[2]); ri[2] = fmaf(eyi[s], pv.z, ri[2]);
            rr[3] = fmaf(eyr[s], pv.w, rr[3]); ri[3] = fmaf(eyi[s], pv.w, ri[3]);
        }
#pragma unroll
        for (int c = 0; c < NC; ++c) {
            accr[c] = fmaf(exr, rr[c], accr[c]);
            accr[c] = fmaf(-exi, ri[c], accr[c]);
            acci[c] = fmaf(exr, ri[c], acci[c]);
            acci[c] = fmaf(exi, rr[c], acci[c]);
        }
    }

    // reduce across jj (lower 3 bits of lane id)
#pragma unroll
    for (int d = 1; d < 8; d <<= 1) {
#pragma unroll
        for (int c = 0; c < NC; ++c) {
            accr[c] += __shfl_xor(accr[c], d, 64);
            acci[c] += __shfl_xor(acci[c], d, 64);
        }
    }
    if (jj == 0) {
#pragma unroll
        for (int c = 0; c < NC; ++c) {
            int q = (r * NS + sp) * NC + c;   // C-order index into [1][128][16][4]
            if (MODE == 0) {
                if (q < out_size) atomicAdd(&out[q], accr[c]);
            } else {
                int oc = q * 2;
                if (oc + 1 < out_size) {
                    atomicAdd(&out[oc + 0], accr[c]);
                    atomicAdd(&out[oc + 1], acci[c]);
                }
            }
        }
    }
}

extern "C" void kernel_launch(void* const* d_in, const int* in_sizes, int n_in,
                              void* d_out, int out_size, void* d_ws, size_t ws_size,
                              hipStream_t stream) {
    const float* x    = (const float*)d_in[0];
    const float* traj = (const float*)d_in[1];
    const float* csm  = (const float*)d_in[2];
    // d_in[3] = dcf (unused by the reference)
    const float* flow = (const float*)d_in[4];
    float* out = (float*)d_out;
    float* P   = (float*)d_ws;

    hipMemsetAsync(d_out, 0, (size_t)out_size * sizeof(float), stream);

    prep_kernel<<<dim3(NT * NPIX / 256), dim3(256), 0, stream>>>(x, csm, flow, P);
    if (out_size <= NPIX / 2 + 1) {   // 8192-float world: real-cast comparison
        ndft_kernel<0><<<dim3(256), dim3(256), 0, stream>>>(traj, P, out, out_size);
    } else {                          // 16384-float world: interleaved complex
        ndft_kernel<1><<<dim3(256), dim3(256), 0, stream>>>(traj, P, out, out_size);
    }
}

// Round 5
// 98.876 us; speedup vs baseline: 5.5260x; 5.5260x over previous
//
#include <hip/hip_runtime.h>
#include <math.h>

#define N      128
#define NS     16
#define NC     4
#define NT     4
#define NPIX   (N * N)       // 16384

// cis(2*pi*rev) via libm sincosf on a range-reduced radian argument.
__device__ __forceinline__ void cis_rev(float rev, float& c, float& s) {
    float f = rev - rintf(rev);                  // [-0.5, 0.5]
    float ang = 6.28318530717958647692f * f;     // [-pi, pi]
    float ss, cc;
    sincosf(ang, &ss, &cc);
    s = ss;
    c = cc;
}

// P[t][i][j][c] = csm[c,i,j] * im_t[i,j], im_t = nearest-neighbor warp of x.
__global__ __launch_bounds__(256) void prep_kernel(
    const float* __restrict__ x, const float* __restrict__ csm,
    const float* __restrict__ flow, float* __restrict__ P)
{
    int g = blockIdx.x * 256 + threadIdx.x;   // 0 .. NT*NPIX-1
    int t = g >> 14;
    int p = g & (NPIX - 1);
    int i = p >> 7, j = p & (N - 1);
    float f0 = flow[(p * 2 + 0) * NT + t];
    float f1 = flow[(p * 2 + 1) * NT + t];
    int si = (int)rintf((float)i + f0); si = min(max(si, 0), N - 1);
    int sj = (int)rintf((float)j + f1); sj = min(max(sj, 0), N - 1);
    float im = x[si * N + sj];
    float4 v;
    v.x = csm[0 * NPIX + p] * im;
    v.y = csm[1 * NPIX + p] * im;
    v.z = csm[2 * NPIX + p] * im;
    v.w = csm[3 * NPIX + p] * im;
    ((float4*)P)[g] = v;
}

// Main NDFT, restructured for occupancy + ILP.
// Grid: 1024 blocks. Block b -> t = b&3, m-group g8 = b>>2 (8 m-points).
// Wave w (0..3) handles m0 = g8*8 + 2w and m0+1. Lane = j-column; each lane
// owns j0 = lane and j1 = lane+64.
// Math: out[m,c] = sum_j Ey[m,j] * (sum_i Ex[m,i] * P[t,i,j,c])
// Ex generated by complex rotor recurrence (no per-i sincos).
__global__ __launch_bounds__(256, 4) void ndft2_kernel(
    const float* __restrict__ traj, const float4* __restrict__ P,
    float* __restrict__ out, int out_size)
{
    int b    = blockIdx.x;
    int t    = b & 3;
    int g8   = b >> 2;             // 0..255
    int tid  = threadIdx.x;
    int lane = tid & 63;
    int w    = tid >> 6;           // 0..3
    int m0   = g8 * 8 + w * 2;     // even m, 0..2046

    const float4* Pt = P + t * NPIX;
    const float4* p0 = Pt + lane;          // j0 = lane
    const float4* p1 = Pt + 64 + lane;     // j1 = lane + 64

    float exr[2], exi[2];          // rotor state (Ex at current i), per m
    float str[2], sti[2];          // rotor step e^{-2pi i kx}, per m
    float ey0r[2], ey0i[2];        // Ey[m, j0]
    float ey1r[2], ey1i[2];        // Ey[m, j1]
#pragma unroll
    for (int mm = 0; mm < 2; ++mm) {
        int m  = m0 + mm;
        int sp = m >> 7;
        int r  = m & (N - 1);
        float kx = traj[((sp * N + r) * NT + t) * 2 + 0];
        float ky = traj[((sp * N + r) * NT + t) * 2 + 1];
        cis_rev(64.0f * kx, exr[mm], exi[mm]);            // Ex at i=0: -kx*(0-64)
        cis_rev(-kx, str[mm], sti[mm]);                   // step
        float dj0 = (float)lane - 64.0f;                  // j0 - 64
        float dj1 = (float)lane;                          // j1 - 64
        cis_rev(-ky * dj0, ey0r[mm], ey0i[mm]);
        cis_rev(-ky * dj1, ey1r[mm], ey1i[mm]);
    }

    // acc[j-half][m][c], complex
    float a0r[2][NC], a0i[2][NC], a1r[2][NC], a1i[2][NC];
#pragma unroll
    for (int mm = 0; mm < 2; ++mm)
#pragma unroll
        for (int c = 0; c < NC; ++c) {
            a0r[mm][c] = 0.f; a0i[mm][c] = 0.f;
            a1r[mm][c] = 0.f; a1i[mm][c] = 0.f;
        }

#define FMA_STEP(V0, V1)                                                   \
    {                                                                      \
        const float* f0 = (const float*)&(V0);                             \
        const float* f1 = (const float*)&(V1);                             \
        _Pragma("unroll")                                                  \
        for (int mm = 0; mm < 2; ++mm) {                                   \
            _Pragma("unroll")                                              \
            for (int c = 0; c < NC; ++c) {                                 \
                a0r[mm][c] = fmaf(exr[mm], f0[c], a0r[mm][c]);             \
                a0i[mm][c] = fmaf(exi[mm], f0[c], a0i[mm][c]);             \
                a1r[mm][c] = fmaf(exr[mm], f1[c], a1r[mm][c]);             \
                a1i[mm][c] = fmaf(exi[mm], f1[c], a1i[mm][c]);             \
            }                                                              \
        }                                                                  \
        _Pragma("unroll")                                                  \
        for (int mm = 0; mm < 2; ++mm) {                                   \
            float er = exr[mm] * str[mm] - exi[mm] * sti[mm];              \
            float ei = fmaf(exr[mm], sti[mm], exi[mm] * str[mm]);          \
            exr[mm] = er; exi[mm] = ei;                                    \
        }                                                                  \
    }

    float4 v0 = p0[0], v1 = p1[0];
    for (int i = 0; i < N - 1; ++i) {
        float4 n0 = p0[(i + 1) * N];
        float4 n1 = p1[(i + 1) * N];
        FMA_STEP(v0, v1)
        v0 = n0; v1 = n1;
    }
    FMA_STEP(v0, v1)   // i = 127
#undef FMA_STEP

    // Real part of Ey * acc, summed over this lane's two j's.
    float red[2][NC];
#pragma unroll
    for (int mm = 0; mm < 2; ++mm)
#pragma unroll
        for (int c = 0; c < NC; ++c) {
            float v;
            v = ey0r[mm] * a0r[mm][c] - ey0i[mm] * a0i[mm][c];
            v = fmaf(ey1r[mm], a1r[mm][c], v);
            v = fmaf(-ey1i[mm], a1i[mm][c], v);
            red[mm][c] = v;
        }

    // Butterfly reduce over all 64 lanes.
#pragma unroll
    for (int d = 1; d < 64; d <<= 1)
#pragma unroll
        for (int mm = 0; mm < 2; ++mm)
#pragma unroll
            for (int c = 0; c < NC; ++c)
                red[mm][c] += __shfl_xor(red[mm][c], d, 64);

    if (lane == 0) {
#pragma unroll
        for (int mm = 0; mm < 2; ++mm) {
            int m  = m0 + mm;
            int sp = m >> 7;
            int r  = m & (N - 1);
#pragma unroll
            for (int c = 0; c < NC; ++c) {
                int q = (r * NS + sp) * NC + c;   // C-order into [1][128][16][4]
                if (q < out_size) atomicAdd(&out[q], red[mm][c]);
            }
        }
    }
}

extern "C" void kernel_launch(void* const* d_in, const int* in_sizes, int n_in,
                              void* d_out, int out_size, void* d_ws, size_t ws_size,
                              hipStream_t stream) {
    const float* x    = (const float*)d_in[0];
    const float* traj = (const float*)d_in[1];
    const float* csm  = (const float*)d_in[2];
    // d_in[3] = dcf (unused by the reference)
    const float* flow = (const float*)d_in[4];
    float* out = (float*)d_out;
    float* P   = (float*)d_ws;

    hipMemsetAsync(d_out, 0, (size_t)out_size * sizeof(float), stream);

    prep_kernel<<<dim3(NT * NPIX / 256), dim3(256), 0, stream>>>(x, csm, flow, P);
    ndft2_kernel<<<dim3(1024), dim3(256), 0, stream>>>(traj, (const float4*)P, out, out_size);
}

// Round 6
// 98.867 us; speedup vs baseline: 5.5265x; 1.0001x over previous
//
#include <hip/hip_runtime.h>
#include <math.h>

#define N      128
#define NS     16
#define NC     4
#define NT     4
#define NPIX   (N * N)       // 16384

// cis(2*pi*rev) via libm sincosf on a range-reduced radian argument.
__device__ __forceinline__ void cis_rev(float rev, float& c, float& s) {
    float f = rev - rintf(rev);                  // [-0.5, 0.5]
    float ang = 6.28318530717958647692f * f;     // [-pi, pi]
    float ss, cc;
    sincosf(ang, &ss, &cc);
    s = ss;
    c = cc;
}

// P[t][i][j][c] = csm[c,i,j] * im_t[i,j]; block 0 also zeroes d_out
// (replaces the separate memset node).
__global__ __launch_bounds__(256) void prep_kernel(
    const float* __restrict__ x, const float* __restrict__ csm,
    const float* __restrict__ flow, float* __restrict__ P,
    float* __restrict__ out, int out_size)
{
    int g = blockIdx.x * 256 + threadIdx.x;   // 0 .. NT*NPIX-1
    int t = g >> 14;
    int p = g & (NPIX - 1);
    int i = p >> 7, j = p & (N - 1);
    float f0 = flow[(p * 2 + 0) * NT + t];
    float f1 = flow[(p * 2 + 1) * NT + t];
    int si = (int)rintf((float)i + f0); si = min(max(si, 0), N - 1);
    int sj = (int)rintf((float)j + f1); sj = min(max(sj, 0), N - 1);
    float im = x[si * N + sj];
    float4 v;
    v.x = csm[0 * NPIX + p] * im;
    v.y = csm[1 * NPIX + p] * im;
    v.z = csm[2 * NPIX + p] * im;
    v.w = csm[3 * NPIX + p] * im;
    ((float4*)P)[g] = v;
    if (blockIdx.x == 0) {
        for (int k = threadIdx.x; k < out_size; k += 256) out[k] = 0.0f;
    }
}

// NDFT with LDS row staging.
// Grid 2048: b -> ih = b&1 (i-half), t = (b>>1)&3, g8 = b>>3 (8 m-points).
// Wave w handles m0 = g8*8 + 2w, m0+1. Lane owns j0=lane, j1=lane+64.
// Rows of P (2KB each) staged into double-buffered LDS in 4-row chunks;
// each row fetched from L2 once per block (4x traffic cut vs direct reads).
__global__ __launch_bounds__(256, 4) void ndft4_kernel(
    const float* __restrict__ traj, const float4* __restrict__ P,
    float* __restrict__ out, int out_size)
{
    __shared__ float4 rows[2][512];   // [buf][4 rows x 128 j] = 16 KiB

    int b    = blockIdx.x;
    int ih   = b & 1;
    int t    = (b >> 1) & 3;          // b%8 -> XCD sees a single t-plane
    int g8   = b >> 3;                // 0..255
    int tid  = threadIdx.x;
    int lane = tid & 63;
    int w    = tid >> 6;
    int m0   = g8 * 8 + w * 2;

    const float4* Pt = P + t * NPIX + ih * (64 * N);   // this block's 64 rows

    // Issue first chunk loads before the sincos prologue (overlap).
    float4 sA = Pt[tid];
    float4 sB = Pt[tid + 256];

    float exr[2], exi[2], str_[2], sti_[2];
    float ey0r[2], ey0i[2], ey1r[2], ey1i[2];
    float i0 = (float)(ih * 64);
#pragma unroll
    for (int mm = 0; mm < 2; ++mm) {
        int m  = m0 + mm;
        int sp = m >> 7;
        int r  = m & (N - 1);
        float kx = traj[((sp * N + r) * NT + t) * 2 + 0];
        float ky = traj[((sp * N + r) * NT + t) * 2 + 1];
        cis_rev(-kx * (i0 - 64.0f), exr[mm], exi[mm]);   // Ex at i = i0
        cis_rev(-kx, str_[mm], sti_[mm]);                // rotor step
        cis_rev(-ky * ((float)lane - 64.0f), ey0r[mm], ey0i[mm]);
        cis_rev(-ky * (float)lane,           ey1r[mm], ey1i[mm]);
    }

    float a0r[2][NC] = {}, a0i[2][NC] = {};
    float a1r[2][NC] = {}, a1i[2][NC] = {};

#define FMA_STEP(V0, V1)                                                   \
    {                                                                      \
        const float* f0 = (const float*)&(V0);                             \
        const float* f1 = (const float*)&(V1);                             \
        _Pragma("unroll")                                                  \
        for (int mm = 0; mm < 2; ++mm) {                                   \
            _Pragma("unroll")                                              \
            for (int c = 0; c < NC; ++c) {                                 \
                a0r[mm][c] = fmaf(exr[mm], f0[c], a0r[mm][c]);             \
                a0i[mm][c] = fmaf(exi[mm], f0[c], a0i[mm][c]);             \
                a1r[mm][c] = fmaf(exr[mm], f1[c], a1r[mm][c]);             \
                a1i[mm][c] = fmaf(exi[mm], f1[c], a1i[mm][c]);             \
            }                                                              \
        }                                                                  \
        _Pragma("unroll")                                                  \
        for (int mm = 0; mm < 2; ++mm) {                                   \
            float er = exr[mm] * str_[mm] - exi[mm] * sti_[mm];            \
            float ei = fmaf(exr[mm], sti_[mm], exi[mm] * str_[mm]);        \
            exr[mm] = er; exi[mm] = ei;                                    \
        }                                                                  \
    }

    // Pipeline: stage chunk0, prefetch chunk1 into regs.
    rows[0][tid] = sA; rows[0][tid + 256] = sB;
    sA = Pt[512 + tid]; sB = Pt[512 + tid + 256];

    const int NCH = 16;   // 16 chunks x 4 rows = 64 i per block
    for (int g = 0; g < NCH; ++g) {
        __syncthreads();                       // rows[g&1] visible to all
        int nb = (g + 1) & 1;
        if (g + 1 < NCH) { rows[nb][tid] = sA; rows[nb][tid + 256] = sB; }
        if (g + 2 < NCH) {
            sA = Pt[(g + 2) * 512 + tid];
            sB = Pt[(g + 2) * 512 + tid + 256];
        }
        int cb = g & 1;
#pragma unroll
        for (int s = 0; s < 4; ++s) {
            float4 v0 = rows[cb][s * 128 + lane];
            float4 v1 = rows[cb][s * 128 + 64 + lane];
            FMA_STEP(v0, v1)
        }
    }
#undef FMA_STEP

    // Real part of Ey * acc, summed over this lane's two j's.
    float red[2][NC];
#pragma unroll
    for (int mm = 0; mm < 2; ++mm)
#pragma unroll
        for (int c = 0; c < NC; ++c) {
            float v;
            v = ey0r[mm] * a0r[mm][c] - ey0i[mm] * a0i[mm][c];
            v = fmaf(ey1r[mm], a1r[mm][c], v);
            v = fmaf(-ey1i[mm], a1i[mm][c], v);
            red[mm][c] = v;
        }

    // Butterfly reduce over 64 lanes.
#pragma unroll
    for (int d = 1; d < 64; d <<= 1)
#pragma unroll
        for (int mm = 0; mm < 2; ++mm)
#pragma unroll
            for (int c = 0; c < NC; ++c)
                red[mm][c] += __shfl_xor(red[mm][c], d, 64);

    if (lane == 0) {
#pragma unroll
        for (int mm = 0; mm < 2; ++mm) {
            int m  = m0 + mm;
            int sp = m >> 7;
            int r  = m & (N - 1);
#pragma unroll
            for (int c = 0; c < NC; ++c) {
                int q = (r * NS + sp) * NC + c;   // C-order into [1][128][16][4]
                if (q < out_size) atomicAdd(&out[q], red[mm][c]);
            }
        }
    }
}

extern "C" void kernel_launch(void* const* d_in, const int* in_sizes, int n_in,
                              void* d_out, int out_size, void* d_ws, size_t ws_size,
                              hipStream_t stream) {
    const float* x    = (const float*)d_in[0];
    const float* traj = (const float*)d_in[1];
    const float* csm  = (const float*)d_in[2];
    // d_in[3] = dcf (unused by the reference)
    const float* flow = (const float*)d_in[4];
    float* out = (float*)d_out;
    float* P   = (float*)d_ws;

    prep_kernel<<<dim3(NT * NPIX / 256), dim3(256), 0, stream>>>(x, csm, flow, P, out, out_size);
    ndft4_kernel<<<dim3(2048), dim3(256), 0, stream>>>(traj, (const float4*)P, out, out_size);
}